// Round 2
// baseline (8973.929 us; speedup 1.0000x reference)
//
#include <hip/hip_runtime.h>

typedef unsigned short u16;
typedef __attribute__((ext_vector_type(8))) short short8;
typedef __attribute__((ext_vector_type(4))) short short4v;
typedef __attribute__((ext_vector_type(4))) float f32x4;

#define B_    64
#define S_    512
#define E_    512
#define H_    512
#define NSEG_ 64

// ---------- helpers ----------
__device__ __forceinline__ float bf2f(u16 u) {
    union { unsigned int i; float f; } x; x.i = ((unsigned int)u) << 16; return x.f;
}
__device__ __forceinline__ u16 f2bf(float f) {
    union { float f; unsigned int i; } x; x.f = f;
    unsigned int r = x.i + 0x7fffu + ((x.i >> 16) & 1u);
    return (u16)(r >> 16);
}
__device__ __forceinline__ f32x4 mfma16(short8 a, short8 b, f32x4 c) {
    return __builtin_amdgcn_mfma_f32_16x16x32_bf16(a, b, c, 0, 0, 0);
}
__device__ __forceinline__ float sigmoidf_(float x) { return 1.f / (1.f + __expf(-x)); }
__device__ __forceinline__ float tanhf_(float x) {
    float e = __expf(-2.f * fabsf(x));
    float t = (1.f - e) / (1.f + e);
    return x < 0.f ? -t : t;
}

// workspace layout (bytes) — all inputs are FP32; bf16 copies live in ws.
// embb : u16[50000*512]            @ 0           (51,200,000)
// wihbb: u16[2][1536][512]         @ 51,200,000  ( 3,145,728)
// whhbb: u16[2][1536][512]         @ 54,345,728  ( 3,145,728)
// hbuf : u16[2 dir][2 par][64][512]@ 57,491,456  (   262,144)
// cnt  : int[2][512]               @ 57,753,600  (     4,096)
// xp   : u16[2][32][64][512][3][16]@ 57,757,696  (201,326,592)  -> end ~259 MB
#define EMBB_OFF  0
#define WIHB_OFF  51200000
#define WHHB_OFF  54345728
#define HBUF_OFF  57491456
#define CNT_OFF   57753600
#define XP_OFF    57757696

// ---------- prep: fp32 -> bf16 conversions + zero hbuf/cnt ----------
__global__ __launch_bounds__(256) void prep_kernel(
    const float* __restrict__ emb,
    const float* __restrict__ wih_f, const float* __restrict__ whh_f,
    const float* __restrict__ wih_b, const float* __restrict__ whh_b,
    u16* __restrict__ embb, u16* __restrict__ wihbb, u16* __restrict__ whhbb,
    u16* __restrict__ hbuf, int* __restrict__ cnt)
{
    const int nt = gridDim.x * 256;
    const int i = blockIdx.x * 256 + threadIdx.x;

    const float4* e4 = (const float4*)emb;
    short4v* eo = (short4v*)embb;
    for (int k = i; k < 6400000; k += nt) {           // 25,600,000 / 4
        float4 v = e4[k];
        short4v o = { (short)f2bf(v.x), (short)f2bf(v.y), (short)f2bf(v.z), (short)f2bf(v.w) };
        eo[k] = o;
    }
    // weights: each [1536][512] = 786432 elems = 196608 float4
    const float4* wf[4] = { (const float4*)wih_f, (const float4*)wih_b,
                            (const float4*)whh_f, (const float4*)whh_b };
    short4v* wo[4] = { (short4v*)wihbb, (short4v*)(wihbb + 786432),
                       (short4v*)whhbb, (short4v*)(whhbb + 786432) };
#pragma unroll
    for (int a = 0; a < 4; ++a) {
        for (int k = i; k < 196608; k += nt) {
            float4 v = wf[a][k];
            short4v o = { (short)f2bf(v.x), (short)f2bf(v.y), (short)f2bf(v.z), (short)f2bf(v.w) };
            wo[a][k] = o;
        }
    }
    int* hz = (int*)hbuf;
    for (int k = i; k < 65536; k += nt) hz[k] = 0;    // 262144 B
    for (int k = i; k < 1024; k += nt) cnt[k] = 0;
}

// ---------- input projection: xp = emb[seq] @ w_ih_d^T + b_ih_d ----------
// M = 32768, N = 3072 (dir0 1536 | dir1 1536), K = 512. 128x128 tile per wg.
__global__ __launch_bounds__(256) void proj_kernel(
    const int* __restrict__ seq, const u16* __restrict__ embb,
    const u16* __restrict__ wihbb,
    const float* __restrict__ b_ih_f, const float* __restrict__ b_ih_b,
    u16* __restrict__ xp)
{
    const int bid = blockIdx.x;            // 256 * 24
    const int mt = bid / 24, nt = bid % 24;
    const int tid = threadIdx.x;
    const int w = tid >> 6, l = tid & 63;
    const int q = l >> 4, col = l & 15;
    const int M0 = mt * 128 + (w >> 1) * 64;
    const int N0 = nt * 128 + (w & 1) * 64;

    const u16* arow[4];
#pragma unroll
    for (int ai = 0; ai < 4; ++ai) {
        const int tok = seq[M0 + ai * 16 + col];
        arow[ai] = embb + (long)tok * E_;
    }
    const u16* brow[4];
#pragma unroll
    for (int bi = 0; bi < 4; ++bi)
        brow[bi] = wihbb + (long)(N0 + bi * 16 + col) * E_;

    f32x4 acc[4][4];
#pragma unroll
    for (int ai = 0; ai < 4; ++ai)
#pragma unroll
        for (int bi = 0; bi < 4; ++bi) acc[ai][bi] = (f32x4){0,0,0,0};

    for (int k = 0; k < 16; ++k) {
        const int ko = k * 32 + q * 8;
        short8 a[4], b[4];
#pragma unroll
        for (int ai = 0; ai < 4; ++ai) a[ai] = *(const short8*)(arow[ai] + ko);
#pragma unroll
        for (int bi = 0; bi < 4; ++bi) b[bi] = *(const short8*)(brow[bi] + ko);
#pragma unroll
        for (int ai = 0; ai < 4; ++ai)
#pragma unroll
            for (int bi = 0; bi < 4; ++bi)
                acc[ai][bi] = mfma16(a[ai], b[bi], acc[ai][bi]);
    }

    // epilogue: row m = M0+ai*16+q*4+i, col n = N0+bi*16+col
#pragma unroll
    for (int bi = 0; bi < 4; ++bi) {
        const int n = N0 + bi * 16 + col;
        const int dir = (n >= 1536) ? 1 : 0;
        const int j = n - dir * 1536;
        const int g = j >> 9, u = j & 511, uc = u >> 4;
        const float bias = dir ? b_ih_b[j] : b_ih_f[j];
        const long base = (long)(dir * 32 + uc) * (64L * 512 * 48) + g * 16 + col;
#pragma unroll
        for (int ai = 0; ai < 4; ++ai) {
#pragma unroll
            for (int i = 0; i < 4; ++i) {
                const int m = M0 + ai * 16 + q * 4 + i;
                const int bs = m >> 9, s = m & 511;
                xp[base + ((long)bs * 512 + s) * 48] = f2bf(acc[ai][bi][i] + bias);
            }
        }
    }
}

// ---------- recurrence + fused segment max ----------
// 64 wgs = 2 dirs x 32 unit-chunks; per-dir (32 wg) device barrier per step.
__global__ __launch_bounds__(256, 1) void rnn_kernel(
    const int* __restrict__ lens, const int* __restrict__ layout,
    const u16* __restrict__ whhbb,
    const float* __restrict__ b_hh_f, const float* __restrict__ b_hh_b,
    const u16* __restrict__ xp, u16* __restrict__ hbuf, int* __restrict__ cnt,
    float* __restrict__ out)
{
    const int bid = blockIdx.x;            // 64
    const int dir = bid >> 5, uc = bid & 31;
    const int u0 = uc * 16;
    const int tid = threadIdx.x;
    const int w = tid >> 6, l = tid & 63;
    const int q = l >> 4, col = l & 15;
    const int u = u0 + col;

    // preload W_hh chunk as MFMA B-fragments: 16 ksteps x 3 gates (192 VGPRs)
    const u16* Whh = whhbb + (long)dir * (3 * H_ * H_);
    short8 wreg[16][3];
#pragma unroll
    for (int k = 0; k < 16; ++k)
#pragma unroll
        for (int g = 0; g < 3; ++g)
            wreg[k][g] = *(const short8*)(Whh + (long)(g * 512 + u0 + col) * H_ + k * 32 + q * 8);

    const float* bhh = dir ? b_hh_b : b_hh_f;
    const float bh0 = bhh[0 * 512 + u];
    const float bh1 = bhh[1 * 512 + u];
    const float bh2 = bhh[2 * 512 + u];

    int samp[4], Ls[4], seg[4], bnd[4];
    float hm[4], mx[4];
    bool done[4];
#pragma unroll
    for (int i = 0; i < 4; ++i) {
        samp[i] = w * 16 + q * 4 + i;
        Ls[i] = lens[samp[i]];
        hm[i] = 0.f;
        mx[i] = -3.4e38f;
        done[i] = false;
        if (dir == 0) { seg[i] = 0; bnd[i] = layout[samp[i] * 65 + 1]; }
        else          { seg[i] = 63; bnd[i] = layout[samp[i] * 65 + 63]; }
    }
    const int asamp = w * 16 + col;        // A-fragment row (sample)

    const u16* xpb = xp + (long)(dir * 32 + uc) * (64L * 512 * 48);
    u16* hb_base = hbuf + (long)dir * 2 * B_ * H_;
    int* cntd = cnt + dir * 512;

    for (int t = 0; t < 512; ++t) {
        // xp gate inputs for step t (independent of h -> issue before barrier)
        float xr[4], xz[4], xn[4];
        int pv[4]; bool val[4];
#pragma unroll
        for (int i = 0; i < 4; ++i) {
            const int L = Ls[i];
            val[i] = (t < L);
            int p = dir ? (L - 1 - t) : t;
            if (p < 0) p = 0;
            pv[i] = p;
            const u16* xq = xpb + ((long)samp[i] * 512 + p) * 48;
            xr[i] = bf2f(xq[0 * 16 + col]);
            xz[i] = bf2f(xq[1 * 16 + col]);
            xn[i] = bf2f(xq[2 * 16 + col]);
        }

        if (t > 0) {  // device barrier: all 32 same-dir wgs finished step t-1
            __threadfence();
            __syncthreads();
            if (tid == 0) {
                __hip_atomic_fetch_add(&cntd[t], 1, __ATOMIC_RELEASE, __HIP_MEMORY_SCOPE_AGENT);
                while (__hip_atomic_load(&cntd[t], __ATOMIC_RELAXED, __HIP_MEMORY_SCOPE_AGENT) < 32)
                    __builtin_amdgcn_s_sleep(2);
            }
            __syncthreads();
            __threadfence();
        }

        // gh = h_prev @ W_chunk^T (fp32 accum)
        const u16* hr = hb_base + (long)(t & 1) * B_ * H_ + (long)asamp * H_;
        f32x4 ar = {0,0,0,0}, az = {0,0,0,0}, an = {0,0,0,0};
#pragma unroll
        for (int k = 0; k < 16; ++k) {
            short8 a = *(const short8*)(hr + k * 32 + q * 8);
            ar = mfma16(a, wreg[k][0], ar);
            az = mfma16(a, wreg[k][1], az);
            an = mfma16(a, wreg[k][2], an);
        }

        u16* hw = hb_base + (long)((t + 1) & 1) * B_ * H_;
#pragma unroll
        for (int i = 0; i < 4; ++i) {
            const float r = sigmoidf_(xr[i] + ar[i] + bh0);
            const float z = sigmoidf_(xz[i] + az[i] + bh1);
            const float n = tanhf_(xn[i] + r * (an[i] + bh2));
            const float hnew = (1.f - z) * n + z * hm[i];
            if (val[i]) {
                hm[i] = hnew;
                // fused ragged segment-max (positions monotone per direction)
                if (dir == 0) {
                    while (t >= bnd[i] && seg[i] < 63) {
                        out[((long)samp[i] * 64 + seg[i]) * 1024 + u] = mx[i];
                        seg[i]++;
                        bnd[i] = layout[samp[i] * 65 + seg[i] + 1];
                        mx[i] = -3.4e38f;
                    }
                } else {
                    while (pv[i] < bnd[i] && seg[i] > 0) {
                        out[((long)samp[i] * 64 + seg[i]) * 1024 + 512 + u] = mx[i];
                        seg[i]--;
                        bnd[i] = layout[samp[i] * 65 + seg[i]];
                        mx[i] = -3.4e38f;
                    }
                }
                mx[i] = fmaxf(mx[i], hnew);
            } else if (!done[i]) {
                out[((long)samp[i] * 64 + seg[i]) * 1024 + dir * 512 + u] = mx[i];
                done[i] = true;
            }
            hw[(long)samp[i] * H_ + u] = f2bf(hm[i]);
        }
    }

#pragma unroll
    for (int i = 0; i < 4; ++i) {
        if (!done[i])  // full-length samples: flush last segment
            out[((long)samp[i] * 64 + seg[i]) * 1024 + dir * 512 + u] = mx[i];
        // final hidden: out[4194304 + dir*B*H + b*H + u]
        out[4194304 + dir * (B_ * H_) + samp[i] * H_ + u] = hm[i];
    }
}

// ---------- launch ----------
extern "C" void kernel_launch(void* const* d_in, const int* in_sizes, int n_in,
                              void* d_out, int out_size, void* d_ws, size_t ws_size,
                              hipStream_t stream) {
    const int*   seq    = (const int*)d_in[0];
    const int*   lens   = (const int*)d_in[1];
    // d_in[2] = hidden (unused by reference)
    const int*   layout = (const int*)d_in[3];
    const float* emb    = (const float*)d_in[4];
    const float* w_ih_f = (const float*)d_in[5];
    const float* w_hh_f = (const float*)d_in[6];
    const float* b_ih_f = (const float*)d_in[7];
    const float* b_hh_f = (const float*)d_in[8];
    const float* w_ih_b = (const float*)d_in[9];
    const float* w_hh_b = (const float*)d_in[10];
    const float* b_ih_b = (const float*)d_in[11];
    const float* b_hh_b = (const float*)d_in[12];
    float* out = (float*)d_out;
    char* ws = (char*)d_ws;

    u16* embb  = (u16*)(ws + EMBB_OFF);
    u16* wihbb = (u16*)(ws + WIHB_OFF);
    u16* whhbb = (u16*)(ws + WHHB_OFF);
    u16* hbuf  = (u16*)(ws + HBUF_OFF);
    int* cnt   = (int*)(ws + CNT_OFF);
    u16* xp    = (u16*)(ws + XP_OFF);

    prep_kernel<<<2048, 256, 0, stream>>>(emb, w_ih_f, w_hh_f, w_ih_b, w_hh_b,
                                          embb, wihbb, whhbb, hbuf, cnt);
    proj_kernel<<<256 * 24, 256, 0, stream>>>(seq, embb, wihbb, b_ih_f, b_ih_b, xp);
    rnn_kernel<<<64, 256, 0, stream>>>(lens, layout, whhbb, b_hh_f, b_hh_b,
                                       xp, hbuf, cnt, out);
}

// Round 3
// 3532.186 us; speedup vs baseline: 2.5406x; 2.5406x over previous
//
#include <hip/hip_runtime.h>

typedef unsigned short u16;
typedef __attribute__((ext_vector_type(8))) short short8;
typedef __attribute__((ext_vector_type(4))) short short4v;
typedef __attribute__((ext_vector_type(4))) float f32x4;

#define B_    64
#define S_    512
#define E_    512
#define H_    512
#define NSEG_ 64

// ---------- helpers ----------
__device__ __forceinline__ float bf2f(u16 u) {
    union { unsigned int i; float f; } x; x.i = ((unsigned int)u) << 16; return x.f;
}
__device__ __forceinline__ u16 f2bf(float f) {
    union { float f; unsigned int i; } x; x.f = f;
    unsigned int r = x.i + 0x7fffu + ((x.i >> 16) & 1u);
    return (u16)(r >> 16);
}
__device__ __forceinline__ f32x4 mfma16(short8 a, short8 b, f32x4 c) {
    return __builtin_amdgcn_mfma_f32_16x16x32_bf16(a, b, c, 0, 0, 0);
}
__device__ __forceinline__ float sigmoidf_(float x) { return 1.f / (1.f + __expf(-x)); }
__device__ __forceinline__ float tanhf_(float x) {
    float e = __expf(-2.f * fabsf(x));
    float t = (1.f - e) / (1.f + e);
    return x < 0.f ? -t : t;
}

// workspace layout (bytes) — all inputs are FP32; bf16 copies live in ws.
#define EMBB_OFF  0
#define WIHB_OFF  51200000
#define WHHB_OFF  54345728
#define HBUF_OFF  57491456
#define CNT_OFF   57753600
#define XP_OFF    57757696

// ---------- prep: fp32 -> bf16 conversions + zero hbuf/cnt ----------
__global__ __launch_bounds__(256) void prep_kernel(
    const float* __restrict__ emb,
    const float* __restrict__ wih_f, const float* __restrict__ whh_f,
    const float* __restrict__ wih_b, const float* __restrict__ whh_b,
    u16* __restrict__ embb, u16* __restrict__ wihbb, u16* __restrict__ whhbb,
    u16* __restrict__ hbuf, int* __restrict__ cnt)
{
    const int nt = gridDim.x * 256;
    const int i = blockIdx.x * 256 + threadIdx.x;

    const float4* e4 = (const float4*)emb;
    short4v* eo = (short4v*)embb;
    for (int k = i; k < 6400000; k += nt) {
        float4 v = e4[k];
        short4v o = { (short)f2bf(v.x), (short)f2bf(v.y), (short)f2bf(v.z), (short)f2bf(v.w) };
        eo[k] = o;
    }
    const float4* wf[4] = { (const float4*)wih_f, (const float4*)wih_b,
                            (const float4*)whh_f, (const float4*)whh_b };
    short4v* wo[4] = { (short4v*)wihbb, (short4v*)(wihbb + 786432),
                       (short4v*)whhbb, (short4v*)(whhbb + 786432) };
#pragma unroll
    for (int a = 0; a < 4; ++a) {
        for (int k = i; k < 196608; k += nt) {
            float4 v = wf[a][k];
            short4v o = { (short)f2bf(v.x), (short)f2bf(v.y), (short)f2bf(v.z), (short)f2bf(v.w) };
            wo[a][k] = o;
        }
    }
    int* hz = (int*)hbuf;
    for (int k = i; k < 65536; k += nt) hz[k] = 0;
    for (int k = i; k < 1024; k += nt) cnt[k] = 0;
}

// ---------- input projection: xp = emb[seq] @ w_ih_d^T + b_ih_d ----------
__global__ __launch_bounds__(256) void proj_kernel(
    const int* __restrict__ seq, const u16* __restrict__ embb,
    const u16* __restrict__ wihbb,
    const float* __restrict__ b_ih_f, const float* __restrict__ b_ih_b,
    u16* __restrict__ xp)
{
    const int bid = blockIdx.x;            // 256 * 24
    const int mt = bid / 24, nt = bid % 24;
    const int tid = threadIdx.x;
    const int w = tid >> 6, l = tid & 63;
    const int q = l >> 4, col = l & 15;
    const int M0 = mt * 128 + (w >> 1) * 64;
    const int N0 = nt * 128 + (w & 1) * 64;

    const u16* arow[4];
#pragma unroll
    for (int ai = 0; ai < 4; ++ai) {
        const int tok = seq[M0 + ai * 16 + col];
        arow[ai] = embb + (long)tok * E_;
    }
    const u16* brow[4];
#pragma unroll
    for (int bi = 0; bi < 4; ++bi)
        brow[bi] = wihbb + (long)(N0 + bi * 16 + col) * E_;

    f32x4 acc[4][4];
#pragma unroll
    for (int ai = 0; ai < 4; ++ai)
#pragma unroll
        for (int bi = 0; bi < 4; ++bi) acc[ai][bi] = (f32x4){0,0,0,0};

    for (int k = 0; k < 16; ++k) {
        const int ko = k * 32 + q * 8;
        short8 a[4], b[4];
#pragma unroll
        for (int ai = 0; ai < 4; ++ai) a[ai] = *(const short8*)(arow[ai] + ko);
#pragma unroll
        for (int bi = 0; bi < 4; ++bi) b[bi] = *(const short8*)(brow[bi] + ko);
#pragma unroll
        for (int ai = 0; ai < 4; ++ai)
#pragma unroll
            for (int bi = 0; bi < 4; ++bi)
                acc[ai][bi] = mfma16(a[ai], b[bi], acc[ai][bi]);
    }

#pragma unroll
    for (int bi = 0; bi < 4; ++bi) {
        const int n = N0 + bi * 16 + col;
        const int dir = (n >= 1536) ? 1 : 0;
        const int j = n - dir * 1536;
        const int g = j >> 9, u = j & 511, uc = u >> 4;
        const float bias = dir ? b_ih_b[j] : b_ih_f[j];
        const long base = (long)(dir * 32 + uc) * (64L * 512 * 48) + g * 16 + col;
#pragma unroll
        for (int ai = 0; ai < 4; ++ai) {
#pragma unroll
            for (int i = 0; i < 4; ++i) {
                const int m = M0 + ai * 16 + q * 4 + i;
                const int bs = m >> 9, s = m & 511;
                xp[base + ((long)bs * 512 + s) * 48] = f2bf(acc[ai][bi][i] + bias);
            }
        }
    }
}

// ---------- recurrence + fused segment max ----------
// 64 wgs = 2 dirs x 32 unit-chunks; per-dir (32 wg) device barrier per step.
// Barrier idiom: h exchanged via sc0sc1 write-through stores (relaxed SYSTEM
// atomics) -> __syncthreads drains vmcnt -> relaxed flag add -> relaxed spin
// -> one acquire load (buffer_inv only, no wbl2) -> plain fresh loads.
__global__ __launch_bounds__(256, 1) void rnn_kernel(
    const int* __restrict__ lens, const int* __restrict__ layout,
    const u16* __restrict__ whhbb,
    const float* __restrict__ b_hh_f, const float* __restrict__ b_hh_b,
    const u16* __restrict__ xp, u16* __restrict__ hbuf, int* __restrict__ cnt,
    float* __restrict__ out)
{
    const int bid = blockIdx.x;            // 64
    const int dir = bid >> 5, uc = bid & 31;
    const int u0 = uc * 16;
    const int tid = threadIdx.x;
    const int w = tid >> 6, l = tid & 63;
    const int q = l >> 4, col = l & 15;
    const int u = u0 + col;

    // preload W_hh chunk as MFMA B-fragments: 16 ksteps x 3 gates
    const u16* Whh = whhbb + (long)dir * (3 * H_ * H_);
    short8 wreg[16][3];
#pragma unroll
    for (int k = 0; k < 16; ++k)
#pragma unroll
        for (int g = 0; g < 3; ++g)
            wreg[k][g] = *(const short8*)(Whh + (long)(g * 512 + u0 + col) * H_ + k * 32 + q * 8);

    const float* bhh = dir ? b_hh_b : b_hh_f;
    const float bh0 = bhh[0 * 512 + u];
    const float bh1 = bhh[1 * 512 + u];
    const float bh2 = bhh[2 * 512 + u];

    int samp[4], Ls[4], seg[4], bnd[4];
    float hm[4], mx[4];
    bool done[4];
#pragma unroll
    for (int i = 0; i < 4; ++i) {
        samp[i] = w * 16 + q * 4 + i;
        Ls[i] = lens[samp[i]];
        hm[i] = 0.f;
        mx[i] = -3.4e38f;
        done[i] = false;
        if (dir == 0) { seg[i] = 0; bnd[i] = layout[samp[i] * 65 + 1]; }
        else          { seg[i] = 63; bnd[i] = layout[samp[i] * 65 + 63]; }
    }
    const int asamp = w * 16 + col;        // A-fragment row (sample)

    const u16* xpb = xp + (long)(dir * 32 + uc) * (64L * 512 * 48);
    u16* hb_base = hbuf + (long)dir * 2 * B_ * H_;
    int* cntd = cnt + dir * 512;

    // xp gate inputs for the CURRENT step (software-pipelined)
    u16 cxr[4], cxz[4], cxn[4];
    int cpv[4]; bool cval[4];
#pragma unroll
    for (int i = 0; i < 4; ++i) {
        const int L = Ls[i];
        cval[i] = (0 < L);
        int p = dir ? (L - 1) : 0;
        if (p < 0) p = 0;
        cpv[i] = p;
        const u16* xq = xpb + ((long)samp[i] * 512 + p) * 48;
        cxr[i] = xq[0 * 16 + col];
        cxz[i] = xq[1 * 16 + col];
        cxn[i] = xq[2 * 16 + col];
    }

    for (int t = 0; t < 512; ++t) {
        if (t > 0) {  // device barrier: all 32 same-dir wgs finished step t-1
            __syncthreads();   // drains vmcnt: h sc-stores + xp prefetch ack'ed
            if (tid == 0) {
                __hip_atomic_fetch_add(&cntd[t], 1, __ATOMIC_RELAXED, __HIP_MEMORY_SCOPE_SYSTEM);
                while (__hip_atomic_load(&cntd[t], __ATOMIC_RELAXED, __HIP_MEMORY_SCOPE_SYSTEM) < 32)
                    __builtin_amdgcn_s_sleep(1);
                (void)__hip_atomic_load(&cntd[t], __ATOMIC_ACQUIRE, __HIP_MEMORY_SCOPE_SYSTEM);
            }
            __syncthreads();
        }

        // gh = h_prev @ W_chunk^T (fp32 accum) — plain loads are fresh post-inv
        const u16* hr = hb_base + (long)(t & 1) * B_ * H_ + (long)asamp * H_;
        short8 afrag[16];
#pragma unroll
        for (int k = 0; k < 16; ++k)
            afrag[k] = *(const short8*)(hr + k * 32 + q * 8);

        // prefetch next step's xp (latency hidden under MFMA + next barrier)
        u16 nxr[4], nxz[4], nxn[4];
        int npv[4]; bool nval[4];
        const int tn = t + 1;
        if (tn < 512) {
#pragma unroll
            for (int i = 0; i < 4; ++i) {
                const int L = Ls[i];
                nval[i] = (tn < L);
                int p = dir ? (L - 1 - tn) : tn;
                if (p < 0) p = 0;
                npv[i] = p;
                const u16* xq = xpb + ((long)samp[i] * 512 + p) * 48;
                nxr[i] = xq[0 * 16 + col];
                nxz[i] = xq[1 * 16 + col];
                nxn[i] = xq[2 * 16 + col];
            }
        } else {
#pragma unroll
            for (int i = 0; i < 4; ++i) { nxr[i] = nxz[i] = nxn[i] = 0; npv[i] = 0; nval[i] = false; }
        }

        f32x4 ar = {0,0,0,0}, az = {0,0,0,0}, an = {0,0,0,0};
#pragma unroll
        for (int k = 0; k < 16; ++k) {
            ar = mfma16(afrag[k], wreg[k][0], ar);
            az = mfma16(afrag[k], wreg[k][1], az);
            an = mfma16(afrag[k], wreg[k][2], an);
        }

        u16* hw = hb_base + (long)((t + 1) & 1) * B_ * H_;
#pragma unroll
        for (int i = 0; i < 4; ++i) {
            const float r = sigmoidf_(bf2f(cxr[i]) + ar[i] + bh0);
            const float z = sigmoidf_(bf2f(cxz[i]) + az[i] + bh1);
            const float n = tanhf_(bf2f(cxn[i]) + r * (an[i] + bh2));
            const float hnew = (1.f - z) * n + z * hm[i];
            if (cval[i]) {
                hm[i] = hnew;
                // fused ragged segment-max (positions monotone per direction)
                if (dir == 0) {
                    while (t >= bnd[i] && seg[i] < 63) {
                        out[((long)samp[i] * 64 + seg[i]) * 1024 + u] = mx[i];
                        seg[i]++;
                        bnd[i] = layout[samp[i] * 65 + seg[i] + 1];
                        mx[i] = -3.4e38f;
                    }
                } else {
                    while (cpv[i] < bnd[i] && seg[i] > 0) {
                        out[((long)samp[i] * 64 + seg[i]) * 1024 + 512 + u] = mx[i];
                        seg[i]--;
                        bnd[i] = layout[samp[i] * 65 + seg[i]];
                        mx[i] = -3.4e38f;
                    }
                }
                mx[i] = fmaxf(mx[i], hnew);
            } else if (!done[i]) {
                out[((long)samp[i] * 64 + seg[i]) * 1024 + dir * 512 + u] = mx[i];
                done[i] = true;
            }
        }

        // packed write-through h store: even lanes store (u,u+1) as one u32
#pragma unroll
        for (int i = 0; i < 4; ++i) {
            const float other = __shfl_xor(hm[i], 1);
            if ((col & 1) == 0) {
                const unsigned int pk = ((unsigned int)f2bf(other) << 16) | (unsigned int)f2bf(hm[i]);
                __hip_atomic_store((unsigned int*)(hw + (long)samp[i] * H_ + u), pk,
                                   __ATOMIC_RELAXED, __HIP_MEMORY_SCOPE_SYSTEM);
            }
        }

        // rotate pipelined xp regs
#pragma unroll
        for (int i = 0; i < 4; ++i) {
            cxr[i] = nxr[i]; cxz[i] = nxz[i]; cxn[i] = nxn[i];
            cpv[i] = npv[i]; cval[i] = nval[i];
        }
    }

#pragma unroll
    for (int i = 0; i < 4; ++i) {
        if (!done[i])  // full-length samples: flush last segment
            out[((long)samp[i] * 64 + seg[i]) * 1024 + dir * 512 + u] = mx[i];
        // final hidden: out[4194304 + dir*B*H + b*H + u]
        out[4194304 + dir * (B_ * H_) + samp[i] * H_ + u] = hm[i];
    }
}

// ---------- launch ----------
extern "C" void kernel_launch(void* const* d_in, const int* in_sizes, int n_in,
                              void* d_out, int out_size, void* d_ws, size_t ws_size,
                              hipStream_t stream) {
    const int*   seq    = (const int*)d_in[0];
    const int*   lens   = (const int*)d_in[1];
    const int*   layout = (const int*)d_in[3];
    const float* emb    = (const float*)d_in[4];
    const float* w_ih_f = (const float*)d_in[5];
    const float* w_hh_f = (const float*)d_in[6];
    const float* b_ih_f = (const float*)d_in[7];
    const float* b_hh_f = (const float*)d_in[8];
    const float* w_ih_b = (const float*)d_in[9];
    const float* w_hh_b = (const float*)d_in[10];
    const float* b_ih_b = (const float*)d_in[11];
    const float* b_hh_b = (const float*)d_in[12];
    float* out = (float*)d_out;
    char* ws = (char*)d_ws;

    u16* embb  = (u16*)(ws + EMBB_OFF);
    u16* wihbb = (u16*)(ws + WIHB_OFF);
    u16* whhbb = (u16*)(ws + WHHB_OFF);
    u16* hbuf  = (u16*)(ws + HBUF_OFF);
    int* cnt   = (int*)(ws + CNT_OFF);
    u16* xp    = (u16*)(ws + XP_OFF);

    prep_kernel<<<2048, 256, 0, stream>>>(emb, w_ih_f, w_hh_f, w_ih_b, w_hh_b,
                                          embb, wihbb, whhbb, hbuf, cnt);
    proj_kernel<<<256 * 24, 256, 0, stream>>>(seq, embb, wihbb, b_ih_f, b_ih_b, xp);
    rnn_kernel<<<64, 256, 0, stream>>>(lens, layout, whhbb, b_hh_f, b_hh_b,
                                       xp, hbuf, cnt, out);
}